// Round 6
// baseline (10699.793 us; speedup 1.0000x reference)
//
#include <hip/hip_runtime.h>
#include <math.h>
#include <stdint.h>

#define B 128
#define S 512
#define V 6000
#define E 100
#define H 256
#define G4 1024   /* 4*H */
#define T 9

/* W split (float4 k-groups, 64 total = 256 cols) */
#define WREG 20            /* cols [0,80)   in VGPRs  (320 KB/CU) */
#define WLDS 3             /* cols [80,92)  in LDS    (48 KB)     */
#define WSTR 41            /* cols [92,256) streamed  (656 KB/step) */

/* workspace byte offsets (256-aligned) */
#define OFF_PEMB_F 0u
#define PEMB_BYTES (V*G4*4u)                    /* 24,576,000 */
#define OFF_PEMB_B (OFF_PEMB_F + PEMB_BYTES)
#define OFF_EMF    (OFF_PEMB_B + PEMB_BYTES)    /* 49,152,000 */
#define EM_BYTES   (B*S*T*4u)                   /* 2,359,296 */
#define OFF_EMB    (OFF_EMF + EM_BYTES)
#define OFF_BP     (OFF_EMB + EM_BYTES)         /* 53,870,592 */
#define BP_BYTES   ((S-1)*B*16u)                /* 1,046,528 */
#define OFF_LT     (OFF_BP + BP_BYTES)
#define OFF_PT     (OFF_LT + 512u)
/* Streamed-W (2 dirs x 41 groups x 1024 rows x 16 B = 1,343,488 B) OVERLAPS
   the BP/LT/PT region: k_prep writes + k_lstm reads it strictly BEFORE
   k_vit/k_back write BP/LT/PT (stream-ordered). Stays under the R5
   footprint high-water mark. */
#define OFF_WSTREAM OFF_BP

__device__ __forceinline__ float sigf(float x) { return 1.0f / (1.0f + expf(-x)); }

/* pemb[v][g4] = bias[g4] + sum_e emb[v][e] * W_ih[g4][e],  g4 = q*H + j */
__global__ __launch_bounds__(256) void k_pemb(const float* __restrict__ emb,
                                              const float* __restrict__ wf, const float* __restrict__ bf,
                                              const float* __restrict__ wb, const float* __restrict__ bb,
                                              char* __restrict__ ws) {
    int blk = blockIdx.x;                   /* 0..749 */
    int d   = blk >= 375;
    int vb  = d ? blk - 375 : blk;
    const float* W    = d ? wb : wf;
    const float* bias = d ? bb : bf;
    float* pe = (float*)(ws + (d ? OFF_PEMB_B : OFF_PEMB_F));

    __shared__ float es[16 * E];
    for (int i = threadIdx.x; i < 16 * E; i += 256) es[i] = emb[vb * 16 * E + i];
    __syncthreads();

    int j = threadIdx.x;
    float acc[4][16];
    #pragma unroll
    for (int q = 0; q < 4; q++) {
        float bq = bias[q * H + j];
        #pragma unroll
        for (int v = 0; v < 16; v++) acc[q][v] = bq;
    }
    for (int e = 0; e < E; e++) {
        float w0 = W[(0 * H + j) * E + e];
        float w1 = W[(1 * H + j) * E + e];
        float w2 = W[(2 * H + j) * E + e];
        float w3 = W[(3 * H + j) * E + e];
        #pragma unroll
        for (int v = 0; v < 16; v++) {
            float x = es[v * E + e];
            acc[0][v] += w0 * x; acc[1][v] += w1 * x;
            acc[2][v] += w2 * x; acc[3][v] += w3 * x;
        }
    }
    for (int v = 0; v < 16; v++)
        #pragma unroll
        for (int q = 0; q < 4; q++)
            pe[(vb * 16 + v) * G4 + q * H + j] = acc[q][v];
}

/* streamed-W layout: wstr[(d*WSTR + g)*1024 + r] = {W_d[r][92+4g .. +3]}
   -> per step, lane r loads consecutive float4 (1 KB/wave-inst, coalesced) */
__global__ __launch_bounds__(256) void k_prep(const float* __restrict__ whhf,
                                              const float* __restrict__ whhb,
                                              char* __restrict__ ws) {
    int tid = blockIdx.x * 256 + threadIdx.x;   /* 2*41*1024 = 83968 */
    int d   = tid >= WSTR * 1024;
    int idx = d ? tid - WSTR * 1024 : tid;
    int g = idx >> 10, r = idx & 1023;
    const float* whh = d ? whhb : whhf;
    float4* wstr = (float4*)(ws + OFF_WSTREAM);
    const float4* src = (const float4*)(whh + (size_t)r * H + 4 * WREG + 4 * WLDS);
    wstr[((size_t)(d * WSTR + g) << 10) + r] = src[g];
}

/* Single-CU LSTM: 256 blocks (dir d = blk>>7, batch b = blk&127) x 1024 thr
   (16 waves, 4/SIMD -> 128 VGPR cap). Thread r owns gate row r = q*256+j.
   W row: cols [0,80) in 20 float4 VGPRs, [80,92) in LDS slab, [92,256)
   streamed from L2 each step (656 KB, double-buffered dwordx4).
   No cross-CU communication of any kind. 2 barriers/step. */
__global__ __launch_bounds__(1024, 4) void k_lstm(const int* __restrict__ data,
                                                  const float* __restrict__ whhf,
                                                  const float* __restrict__ whhb,
                                                  const float* __restrict__ mlpW,
                                                  char* __restrict__ ws) {
    int blk = blockIdx.x;
    int d = blk >> 7, b = blk & 127;
    const float* whh = d ? whhb : whhf;
    const float* pe  = (const float*)(ws + (d ? OFF_PEMB_B : OFF_PEMB_F));
    float* emdst = (float*)(ws + (d ? OFF_EMB : OFF_EMF));
    const float4* wstr = (const float4*)(ws + OFF_WSTREAM) + ((size_t)(d * WSTR) << 10);

    __shared__ __align__(16) float hs[H];      /* h_prev, 1 KB */
    __shared__ float4 sW[WLDS << 10];          /* 48 KB */
    __shared__ float  gbuf[G4];                /* 4 KB */
    __shared__ float  red[T][4];
    __shared__ int    toks[S];                 /* 2 KB */

    int r = threadIdx.x;                       /* gate row */

    /* W register groups (cols 0..79) + LDS slab (cols 80..91) */
    float4 wr[WREG];
    const float4* wrow = (const float4*)(whh + (size_t)r * H);
    #pragma unroll
    for (int g = 0; g < WREG; g++) wr[g] = wrow[g];
    #pragma unroll
    for (int g = 0; g < WLDS; g++) sW[(g << 10) + r] = wrow[WREG + g];

    if (r < S) toks[r] = data[b * S + r];
    if (r < 512) toks[512 + r - 512 + 0] = toks[512 + r - 512 + 0]; /* no-op keep simple */
    if (r >= 512 && r < 1024 && (r - 512) < S - 512) {}             /* S == 512: covered above */

    /* emission weights: thread j = r < 256 */
    float mw[T];
    if (r < 256) {
        #pragma unroll
        for (int t = 0; t < T; t++) mw[t] = mlpW[t * (2 * H) + d * H + r];
    }
    if (r < H) hs[r] = 0.0f;
    float cst = 0.0f;
    __syncthreads();

    float pf;
    {
        int sp0 = d ? (S - 1) : 0;
        pf = pe[((size_t)toks[sp0] << 10) + r];
    }

    const float4* hs4 = (const float4*)hs;
    const float4* wsp = wstr + r;

    for (int ss = 0; ss < S; ss++) {
        int sp = d ? (S - 1 - ss) : ss;
        float acc = pf;
        if (ss + 1 < S) {
            int spn = d ? (S - 2 - ss) : (ss + 1);
            pf = pe[((size_t)toks[spn] << 10) + r];
        }

        /* prime streamed double-buffer early (latency overlaps reg phase) */
        float4 s0 = wsp[0];
        float4 s1 = wsp[1 << 10];

        /* register-W phase: cols 0..79 */
        #pragma unroll
        for (int g = 0; g < WREG; g++) {
            float4 h4 = hs4[g];
            float4 w  = wr[g];
            acc = fmaf(w.x, h4.x, acc); acc = fmaf(w.y, h4.y, acc);
            acc = fmaf(w.z, h4.z, acc); acc = fmaf(w.w, h4.w, acc);
        }
        /* LDS-W phase: cols 80..91 */
        #pragma unroll
        for (int g = 0; g < WLDS; g++) {
            float4 w  = sW[(g << 10) + r];
            float4 h4 = hs4[WREG + g];
            acc = fmaf(w.x, h4.x, acc); acc = fmaf(w.y, h4.y, acc);
            acc = fmaf(w.z, h4.z, acc); acc = fmaf(w.w, h4.w, acc);
        }
        /* streamed phase: cols 92..255, 2-deep pipeline */
        #pragma unroll
        for (int g = 0; g < WSTR; g++) {
            float4 w = (g & 1) ? s1 : s0;
            if (g + 2 < WSTR) {
                if (g & 1) s1 = wsp[(size_t)(g + 2) << 10];
                else       s0 = wsp[(size_t)(g + 2) << 10];
            }
            float4 h4 = hs4[WREG + WLDS + g];
            acc = fmaf(w.x, h4.x, acc); acc = fmaf(w.y, h4.y, acc);
            acc = fmaf(w.z, h4.z, acc); acc = fmaf(w.w, h4.w, acc);
        }
        gbuf[r] = acc;
        __syncthreads();   /* B1: gates complete, all hs reads done */

        if (r < H) {
            float gi = gbuf[r], gf = gbuf[H + r], gg = gbuf[2 * H + r], go = gbuf[3 * H + r];
            float ig = sigf(gi), fg = sigf(gf), tg = tanhf(gg), og = sigf(go);
            cst = fg * cst + ig * tg;
            float hn = og * tanhf(cst);
            hs[r] = hn;
            int l = r & 63, wv = r >> 6;
            #pragma unroll
            for (int t = 0; t < T; t++) {
                float v = hn * mw[t];
                v += __shfl_xor(v, 32, 64); v += __shfl_xor(v, 16, 64);
                v += __shfl_xor(v, 8, 64);  v += __shfl_xor(v, 4, 64);
                v += __shfl_xor(v, 2, 64);  v += __shfl_xor(v, 1, 64);
                if (l == 0) red[t][wv] = v;
            }
        }
        __syncthreads();   /* B2: hs updated + red ready */
        if (r < T)
            emdst[((size_t)b * S + sp) * T + r] = red[r][0] + red[r][1] + red[r][2] + red[r][3];
    }
}

/* Viterbi forward: one wave per batch, lane t = tag. Strict-> ascending scan
   matches jnp.argmax first-index tie-breaking. */
__global__ __launch_bounds__(64) void k_vit(const int* __restrict__ data,
                                            const float* __restrict__ strans,
                                            const float* __restrict__ trans,
                                            const float* __restrict__ etrans,
                                            const float* __restrict__ mlpb,
                                            float* __restrict__ out,
                                            char* __restrict__ ws) {
    int b = blockIdx.x, t = threadIdx.x;
    const float* emf = (const float*)(ws + OFF_EMF);
    const float* emb = (const float*)(ws + OFF_EMB);
    char* bp = ws + OFF_BP;
    int*  lt = (int*)(ws + OFF_LT);
    bool act = t < T;

    float trp[T];
    float mb = 0.0f;
    if (act) {
        #pragma unroll
        for (int p = 0; p < T; p++) trp[p] = trans[p * T + t];
        mb = mlpb[t];
    }
    float score = -1e30f;
    if (act) score = strans[t] + emf[(b * S) * T + t] + emb[(b * S) * T + t] + mb;

    for (int s = 1; s < S; s++) {
        float e = 0.0f;
        if (act) e = emf[(b * S + s) * T + t] + emb[(b * S + s) * T + t] + mb;
        float best = __shfl(score, 0, 64) + trp[0];
        int bpi = 0;
        #pragma unroll
        for (int p = 1; p < T; p++) {
            float cand = __shfl(score, p, 64) + trp[p];
            if (cand > best) { best = cand; bpi = p; }
        }
        int m = data[b * S + s] != 0;
        if (act) {
            score = m ? (best + e) : score;
            bp[((size_t)(s - 1) * B + b) * 16 + t] = (char)bpi;
        }
    }
    float fin = act ? score + etrans[t] : -1e30f;
    float bv = __shfl(fin, 0, 64);
    int bi = 0;
    #pragma unroll
    for (int p = 1; p < T; p++) {
        float v = __shfl(fin, p, 64);
        if (v > bv) { bv = v; bi = p; }
    }
    if (t == 0) { out[B * S + b] = bv; lt[b] = bi; }
}

/* Backtrack: thread = batch; bp row address is tag-independent -> pipelined loads */
__global__ __launch_bounds__(128) void k_back(const int* __restrict__ data, char* __restrict__ ws) {
    int b = threadIdx.x;
    const int4* bp4 = (const int4*)(ws + OFF_BP);
    const int*  lt  = (const int*)(ws + OFF_LT);
    int* pt = (int*)(ws + OFF_PT);
    int tag = lt[b];
    pt[(S - 1) * B + b] = tag;
    for (int p = S - 2; p >= 0; p--) {
        int4 r = bp4[(size_t)p * B + b];
        int m = data[b * S + p + 1] != 0;
        unsigned w = (unsigned)(tag < 8 ? (tag < 4 ? r.x : r.y) : r.z);
        int nt = (int)((w >> ((tag & 3) * 8)) & 0xff);
        tag = m ? nt : tag;
        pt[p * B + b] = tag;
    }
}

/* paths -> float output with mask zeroing */
__global__ __launch_bounds__(256) void k_fin(const int* __restrict__ data,
                                             float* __restrict__ out,
                                             const char* __restrict__ ws) {
    int tid = blockIdx.x * 256 + threadIdx.x;   /* 65536 */
    const int* pt = (const int*)(ws + OFF_PT);
    int b = tid >> 9, p = tid & 511;
    out[tid] = (data[tid] != 0) ? (float)pt[p * B + b] : 0.0f;
}

extern "C" void kernel_launch(void* const* d_in, const int* in_sizes, int n_in,
                              void* d_out, int out_size, void* d_ws, size_t ws_size,
                              hipStream_t stream) {
    const int*   data = (const int*)d_in[0];
    /* d_in[1] = mask (bool) — unused; mask == (data != 0) */
    const float* emb  = (const float*)d_in[2];
    const float* wihf = (const float*)d_in[3];
    const float* whhf = (const float*)d_in[4];
    const float* bf   = (const float*)d_in[5];
    const float* wihb = (const float*)d_in[6];
    const float* whhb = (const float*)d_in[7];
    const float* bb   = (const float*)d_in[8];
    const float* mlpW = (const float*)d_in[9];
    const float* mlpb = (const float*)d_in[10];
    const float* st   = (const float*)d_in[11];
    const float* tr   = (const float*)d_in[12];
    const float* et   = (const float*)d_in[13];
    float* out = (float*)d_out;
    char*  ws  = (char*)d_ws;

    hipLaunchKernelGGL(k_pemb, dim3(750),  dim3(256),  0, stream, emb, wihf, bf, wihb, bb, ws);
    hipLaunchKernelGGL(k_prep, dim3(328),  dim3(256),  0, stream, whhf, whhb, ws);
    hipLaunchKernelGGL(k_lstm, dim3(256),  dim3(1024), 0, stream, data, whhf, whhb, mlpW, ws);
    hipLaunchKernelGGL(k_vit,  dim3(128),  dim3(64),   0, stream, data, st, tr, et, mlpb, out, ws);
    hipLaunchKernelGGL(k_back, dim3(1),    dim3(128),  0, stream, data, ws);
    hipLaunchKernelGGL(k_fin,  dim3(256),  dim3(256),  0, stream, data, out, ws);
}

// Round 7
// 5144.601 us; speedup vs baseline: 2.0798x; 2.0798x over previous
//
#include <hip/hip_runtime.h>
#include <math.h>
#include <stdint.h>

#define B 128
#define S 512
#define V 6000
#define E 100
#define H 256
#define G4 1024   /* 4*H */
#define T 9

/* W column split (float4 k-groups, 64 total = 256 cols per row) */
#define WREG 18            /* cols [0,72)  in VGPRs: 2 rows x 18 x 4 = 144 regs */
#define WLDS 3             /* cols [72,84) in LDS slab (48 KB) */
#define WSTR 43            /* cols [84,256) streamed (688 KB/step/dir) */

/* workspace byte offsets (256-aligned) */
#define OFF_PEMB_F 0u
#define PEMB_BYTES (V*G4*4u)                    /* 24,576,000 */
#define OFF_PEMB_B (OFF_PEMB_F + PEMB_BYTES)
#define OFF_EMF    (OFF_PEMB_B + PEMB_BYTES)    /* 49,152,000 */
#define EM_BYTES   (B*S*T*4u)                   /* 2,359,296 */
#define OFF_EMB    (OFF_EMF + EM_BYTES)
#define OFF_BP     (OFF_EMB + EM_BYTES)         /* 53,870,592 */
#define BP_BYTES   ((S-1)*B*16u)                /* 1,046,528 */
#define OFF_LT     (OFF_BP + BP_BYTES)
#define OFF_PT     (OFF_LT + 512u)
/* Streamed-W (2 dirs x 43 groups x 1024 rows x 16 B = 1,409,024 B) OVERLAPS
   the BP/LT/PT region: k_prep writes it and k_lstm reads it strictly BEFORE
   k_vit/k_back write BP/LT/PT (stream-ordered). */
#define OFF_WSTREAM OFF_BP

__device__ __forceinline__ float sigf(float x) { return 1.0f / (1.0f + expf(-x)); }

/* pemb[v][g4] = bias[g4] + sum_e emb[v][e] * W_ih[g4][e],  g4 = q*H + j */
__global__ __launch_bounds__(256) void k_pemb(const float* __restrict__ emb,
                                              const float* __restrict__ wf, const float* __restrict__ bf,
                                              const float* __restrict__ wb, const float* __restrict__ bb,
                                              char* __restrict__ ws) {
    int blk = blockIdx.x;                   /* 0..749 */
    int d   = blk >= 375;
    int vb  = d ? blk - 375 : blk;
    const float* W    = d ? wb : wf;
    const float* bias = d ? bb : bf;
    float* pe = (float*)(ws + (d ? OFF_PEMB_B : OFF_PEMB_F));

    __shared__ float es[16 * E];
    for (int i = threadIdx.x; i < 16 * E; i += 256) es[i] = emb[vb * 16 * E + i];
    __syncthreads();

    int j = threadIdx.x;
    float acc[4][16];
    #pragma unroll
    for (int q = 0; q < 4; q++) {
        float bq = bias[q * H + j];
        #pragma unroll
        for (int v = 0; v < 16; v++) acc[q][v] = bq;
    }
    for (int e = 0; e < E; e++) {
        float w0 = W[(0 * H + j) * E + e];
        float w1 = W[(1 * H + j) * E + e];
        float w2 = W[(2 * H + j) * E + e];
        float w3 = W[(3 * H + j) * E + e];
        #pragma unroll
        for (int v = 0; v < 16; v++) {
            float x = es[v * E + e];
            acc[0][v] += w0 * x; acc[1][v] += w1 * x;
            acc[2][v] += w2 * x; acc[3][v] += w3 * x;
        }
    }
    for (int v = 0; v < 16; v++)
        #pragma unroll
        for (int q = 0; q < 4; q++)
            pe[(vb * 16 + v) * G4 + q * H + j] = acc[q][v];
}

/* streamed-W layout: wstr[(d*WSTR + g)*1024 + r] = {W_d[r][84+4g .. +3]}
   -> per step, lane r loads consecutive float4 (coalesced 1 KB/wave-inst) */
__global__ __launch_bounds__(256) void k_prep(const float* __restrict__ whhf,
                                              const float* __restrict__ whhb,
                                              char* __restrict__ ws) {
    int tid = blockIdx.x * 256 + threadIdx.x;   /* 2*43*1024 = 88064 */
    if (tid >= 2 * WSTR * 1024) return;
    int d   = tid >= WSTR * 1024;
    int idx = d ? tid - WSTR * 1024 : tid;
    int g = idx >> 10, r = idx & 1023;
    const float* whh = d ? whhb : whhf;
    float4* wstr = (float4*)(ws + OFF_WSTREAM);
    const float4* src = (const float4*)(whh + (size_t)r * H + 4 * (WREG + WLDS));
    wstr[((size_t)(d * WSTR + g) << 10) + r] = src[g];
}

/* Single-CU LSTM: 256 blocks (dir d = blk>>7, batch b = blk&127) x 512 thr
   (8 waves, 2/SIMD; launch_bounds(512,2) -> 256-VGPR budget, explicit).
   Thread t owns gate rows t and t+512. Per row: cols [0,72) in VGPRs,
   [72,84) in LDS, [84,256) streamed from L2 (688 KB/step, k-major).
   No cross-CU communication. 2 barriers/step. */
__global__ __launch_bounds__(512, 2) void k_lstm(const int* __restrict__ data,
                                                 const float* __restrict__ whhf,
                                                 const float* __restrict__ whhb,
                                                 const float* __restrict__ mlpW,
                                                 char* __restrict__ ws) {
    int blk = blockIdx.x;
    int d = blk >> 7, b = blk & 127;
    const float* whh = d ? whhb : whhf;
    const float* pe  = (const float*)(ws + (d ? OFF_PEMB_B : OFF_PEMB_F));
    float* emdst = (float*)(ws + (d ? OFF_EMB : OFF_EMF));
    const float4* wstr = (const float4*)(ws + OFF_WSTREAM) + ((size_t)(d * WSTR) << 10);

    __shared__ __align__(16) float hs[H];      /* h_prev, 1 KB */
    __shared__ float4 sW[WLDS << 10];          /* 48 KB */
    __shared__ float  gbuf[G4];                /* 4 KB */
    __shared__ float  red[T][4];
    __shared__ int    toks[S];                 /* 2 KB */

    int t = threadIdx.x;                       /* 0..511 */
    int r0 = t, r1 = t + 512;

    /* W register groups (cols 0..71) for both rows + LDS slab (cols 72..83) */
    const float4* wrow0 = (const float4*)(whh + (size_t)r0 * H);
    const float4* wrow1 = (const float4*)(whh + (size_t)r1 * H);
    float4 wA[WREG], wB[WREG];
    #pragma unroll
    for (int g = 0; g < WREG; g++) { wA[g] = wrow0[g]; wB[g] = wrow1[g]; }
    #pragma unroll
    for (int g = 0; g < WLDS; g++) {
        sW[(g << 10) + r0] = wrow0[WREG + g];
        sW[(g << 10) + r1] = wrow1[WREG + g];
    }

    toks[t] = data[b * S + t];                 /* S == 512 == blockDim */

    float mw[T];
    if (t < 256) {
        #pragma unroll
        for (int tt = 0; tt < T; tt++) mw[tt] = mlpW[tt * (2 * H) + d * H + t];
    }
    if (t < H) hs[t] = 0.0f;
    float cst = 0.0f;
    __syncthreads();

    const float4* hs4 = (const float4*)hs;
    const float4* wsp0 = wstr + r0;
    const float4* wsp1 = wstr + r1;

    float pf0, pf1;
    {
        int sp0 = d ? (S - 1) : 0;
        size_t tok = (size_t)toks[sp0];
        pf0 = pe[(tok << 10) + r0];
        pf1 = pe[(tok << 10) + r1];
    }

    for (int ss = 0; ss < S; ss++) {
        int sp = d ? (S - 1 - ss) : ss;
        float acc0 = pf0, acc1 = pf1;
        if (ss + 1 < S) {
            int spn = d ? (S - 2 - ss) : (ss + 1);
            size_t tok = (size_t)toks[spn];
            pf0 = pe[(tok << 10) + r0];
            pf1 = pe[(tok << 10) + r1];
        }

        /* register-W phase: cols 0..71 */
        #pragma unroll
        for (int g = 0; g < WREG; g++) {
            float4 h4 = hs4[g];
            float4 a = wA[g], bb2 = wB[g];
            acc0 = fmaf(a.x, h4.x, acc0);  acc1 = fmaf(bb2.x, h4.x, acc1);
            acc0 = fmaf(a.y, h4.y, acc0);  acc1 = fmaf(bb2.y, h4.y, acc1);
            acc0 = fmaf(a.z, h4.z, acc0);  acc1 = fmaf(bb2.z, h4.z, acc1);
            acc0 = fmaf(a.w, h4.w, acc0);  acc1 = fmaf(bb2.w, h4.w, acc1);
        }
        /* LDS-W phase: cols 72..83 */
        #pragma unroll
        for (int g = 0; g < WLDS; g++) {
            float4 w0 = sW[(g << 10) + r0];
            float4 w1 = sW[(g << 10) + r1];
            float4 h4 = hs4[WREG + g];
            acc0 = fmaf(w0.x, h4.x, acc0);  acc1 = fmaf(w1.x, h4.x, acc1);
            acc0 = fmaf(w0.y, h4.y, acc0);  acc1 = fmaf(w1.y, h4.y, acc1);
            acc0 = fmaf(w0.z, h4.z, acc0);  acc1 = fmaf(w1.z, h4.z, acc1);
            acc0 = fmaf(w0.w, h4.w, acc0);  acc1 = fmaf(w1.w, h4.w, acc1);
        }
        /* streamed phase: cols 84..255 (bounded pipelining via unroll 4) */
        #pragma unroll 4
        for (int g = 0; g < WSTR; g++) {
            float4 w0 = wsp0[(size_t)g << 10];
            float4 w1 = wsp1[(size_t)g << 10];
            float4 h4 = hs4[WREG + WLDS + g];
            acc0 = fmaf(w0.x, h4.x, acc0);  acc1 = fmaf(w1.x, h4.x, acc1);
            acc0 = fmaf(w0.y, h4.y, acc0);  acc1 = fmaf(w1.y, h4.y, acc1);
            acc0 = fmaf(w0.z, h4.z, acc0);  acc1 = fmaf(w1.z, h4.z, acc1);
            acc0 = fmaf(w0.w, h4.w, acc0);  acc1 = fmaf(w1.w, h4.w, acc1);
        }
        gbuf[r0] = acc0;
        gbuf[r1] = acc1;
        __syncthreads();   /* B1: gates complete, hs reads done */

        if (t < 256) {
            float gi = gbuf[t], gf = gbuf[H + t], gg = gbuf[2 * H + t], go = gbuf[3 * H + t];
            float ig = sigf(gi), fg = sigf(gf), tg = tanhf(gg), og = sigf(go);
            cst = fg * cst + ig * tg;
            float hn = og * tanhf(cst);
            hs[t] = hn;
            int l = t & 63, wv = t >> 6;
            #pragma unroll
            for (int tt = 0; tt < T; tt++) {
                float v = hn * mw[tt];
                v += __shfl_xor(v, 32, 64); v += __shfl_xor(v, 16, 64);
                v += __shfl_xor(v, 8, 64);  v += __shfl_xor(v, 4, 64);
                v += __shfl_xor(v, 2, 64);  v += __shfl_xor(v, 1, 64);
                if (l == 0) red[tt][wv] = v;
            }
        }
        __syncthreads();   /* B2: hs updated + red ready */
        if (t < T)
            emdst[((size_t)b * S + sp) * T + t] = red[t][0] + red[t][1] + red[t][2] + red[t][3];
    }
}

/* Viterbi forward: one wave per batch, lane t = tag. Strict-> ascending scan
   matches jnp.argmax first-index tie-breaking. */
__global__ __launch_bounds__(64) void k_vit(const int* __restrict__ data,
                                            const float* __restrict__ strans,
                                            const float* __restrict__ trans,
                                            const float* __restrict__ etrans,
                                            const float* __restrict__ mlpb,
                                            float* __restrict__ out,
                                            char* __restrict__ ws) {
    int b = blockIdx.x, t = threadIdx.x;
    const float* emf = (const float*)(ws + OFF_EMF);
    const float* emb = (const float*)(ws + OFF_EMB);
    char* bp = ws + OFF_BP;
    int*  lt = (int*)(ws + OFF_LT);
    bool act = t < T;

    float trp[T];
    float mb = 0.0f;
    if (act) {
        #pragma unroll
        for (int p = 0; p < T; p++) trp[p] = trans[p * T + t];
        mb = mlpb[t];
    }
    float score = -1e30f;
    if (act) score = strans[t] + emf[(b * S) * T + t] + emb[(b * S) * T + t] + mb;

    for (int s = 1; s < S; s++) {
        float e = 0.0f;
        if (act) e = emf[(b * S + s) * T + t] + emb[(b * S + s) * T + t] + mb;
        float best = __shfl(score, 0, 64) + trp[0];
        int bpi = 0;
        #pragma unroll
        for (int p = 1; p < T; p++) {
            float cand = __shfl(score, p, 64) + trp[p];
            if (cand > best) { best = cand; bpi = p; }
        }
        int m = data[b * S + s] != 0;
        if (act) {
            score = m ? (best + e) : score;
            bp[((size_t)(s - 1) * B + b) * 16 + t] = (char)bpi;
        }
    }
    float fin = act ? score + etrans[t] : -1e30f;
    float bv = __shfl(fin, 0, 64);
    int bi = 0;
    #pragma unroll
    for (int p = 1; p < T; p++) {
        float v = __shfl(fin, p, 64);
        if (v > bv) { bv = v; bi = p; }
    }
    if (t == 0) { out[B * S + b] = bv; lt[b] = bi; }
}

/* Backtrack: thread = batch; bp row address is tag-independent -> pipelined loads */
__global__ __launch_bounds__(128) void k_back(const int* __restrict__ data, char* __restrict__ ws) {
    int b = threadIdx.x;
    const int4* bp4 = (const int4*)(ws + OFF_BP);
    const int*  lt  = (const int*)(ws + OFF_LT);
    int* pt = (int*)(ws + OFF_PT);
    int tag = lt[b];
    pt[(S - 1) * B + b] = tag;
    for (int p = S - 2; p >= 0; p--) {
        int4 r = bp4[(size_t)p * B + b];
        int m = data[b * S + p + 1] != 0;
        unsigned w = (unsigned)(tag < 8 ? (tag < 4 ? r.x : r.y) : r.z);
        int nt = (int)((w >> ((tag & 3) * 8)) & 0xff);
        tag = m ? nt : tag;
        pt[p * B + b] = tag;
    }
}

/* paths -> float output with mask zeroing */
__global__ __launch_bounds__(256) void k_fin(const int* __restrict__ data,
                                             float* __restrict__ out,
                                             const char* __restrict__ ws) {
    int tid = blockIdx.x * 256 + threadIdx.x;   /* 65536 */
    const int* pt = (const int*)(ws + OFF_PT);
    int b = tid >> 9, p = tid & 511;
    out[tid] = (data[tid] != 0) ? (float)pt[p * B + b] : 0.0f;
}

extern "C" void kernel_launch(void* const* d_in, const int* in_sizes, int n_in,
                              void* d_out, int out_size, void* d_ws, size_t ws_size,
                              hipStream_t stream) {
    const int*   data = (const int*)d_in[0];
    /* d_in[1] = mask (bool) — unused; mask == (data != 0) */
    const float* emb  = (const float*)d_in[2];
    const float* wihf = (const float*)d_in[3];
    const float* whhf = (const float*)d_in[4];
    const float* bf   = (const float*)d_in[5];
    const float* wihb = (const float*)d_in[6];
    const float* whhb = (const float*)d_in[7];
    const float* bb   = (const float*)d_in[8];
    const float* mlpW = (const float*)d_in[9];
    const float* mlpb = (const float*)d_in[10];
    const float* st   = (const float*)d_in[11];
    const float* tr   = (const float*)d_in[12];
    const float* et   = (const float*)d_in[13];
    float* out = (float*)d_out;
    char*  ws  = (char*)d_ws;

    hipLaunchKernelGGL(k_pemb, dim3(750),  dim3(256), 0, stream, emb, wihf, bf, wihb, bb, ws);
    hipLaunchKernelGGL(k_prep, dim3(344),  dim3(256), 0, stream, whhf, whhb, ws);
    hipLaunchKernelGGL(k_lstm, dim3(256),  dim3(512), 0, stream, data, whhf, whhb, mlpW, ws);
    hipLaunchKernelGGL(k_vit,  dim3(128),  dim3(64),  0, stream, data, st, tr, et, mlpb, out, ws);
    hipLaunchKernelGGL(k_back, dim3(1),    dim3(128), 0, stream, data, ws);
    hipLaunchKernelGGL(k_fin,  dim3(256),  dim3(256), 0, stream, data, out, ws);
}

// Round 8
// 4808.271 us; speedup vs baseline: 2.2253x; 1.0699x over previous
//
#include <hip/hip_runtime.h>
#include <math.h>
#include <stdint.h>

#define B 128
#define S 512
#define V 6000
#define E 100
#define H 256
#define G4 1024   /* 4*H */
#define T 9

/* W column split (float4 k-groups, 64 total = 256 cols per row) */
#define WREG 20            /* cols [0,80)  in VGPRs: 2 rows x 20 x 4 = 160 regs, PINNED */
#define WLDS 3             /* cols [80,92) in LDS slab (48 KB) */
#define WSTR 41            /* cols [92,256) streamed (656 KB/step/dir) */

/* workspace byte offsets (256-aligned) */
#define OFF_PEMB_F 0u
#define PEMB_BYTES (V*G4*4u)                    /* 24,576,000 */
#define OFF_PEMB_B (OFF_PEMB_F + PEMB_BYTES)
#define OFF_EMF    (OFF_PEMB_B + PEMB_BYTES)    /* 49,152,000 */
#define EM_BYTES   (B*S*T*4u)                   /* 2,359,296 */
#define OFF_EMB    (OFF_EMF + EM_BYTES)
#define OFF_BP     (OFF_EMB + EM_BYTES)         /* 53,870,592 */
#define BP_BYTES   ((S-1)*B*16u)                /* 1,046,528 */
#define OFF_LT     (OFF_BP + BP_BYTES)
#define OFF_PT     (OFF_LT + 512u)
/* Streamed-W (2 dirs x 41 groups x 1024 rows x 16 B = 1,343,488 B) OVERLAPS
   the BP/LT/PT region: k_prep writes it and k_lstm reads it strictly BEFORE
   k_vit/k_back write BP/LT/PT (stream-ordered). */
#define OFF_WSTREAM OFF_BP

__device__ __forceinline__ float sigf(float x) { return 1.0f / (1.0f + expf(-x)); }

/* pemb[v][g4] = bias[g4] + sum_e emb[v][e] * W_ih[g4][e],  g4 = q*H + j */
__global__ __launch_bounds__(256) void k_pemb(const float* __restrict__ emb,
                                              const float* __restrict__ wf, const float* __restrict__ bf,
                                              const float* __restrict__ wb, const float* __restrict__ bb,
                                              char* __restrict__ ws) {
    int blk = blockIdx.x;                   /* 0..749 */
    int d   = blk >= 375;
    int vb  = d ? blk - 375 : blk;
    const float* W    = d ? wb : wf;
    const float* bias = d ? bb : bf;
    float* pe = (float*)(ws + (d ? OFF_PEMB_B : OFF_PEMB_F));

    __shared__ float es[16 * E];
    for (int i = threadIdx.x; i < 16 * E; i += 256) es[i] = emb[vb * 16 * E + i];
    __syncthreads();

    int j = threadIdx.x;
    float acc[4][16];
    #pragma unroll
    for (int q = 0; q < 4; q++) {
        float bq = bias[q * H + j];
        #pragma unroll
        for (int v = 0; v < 16; v++) acc[q][v] = bq;
    }
    for (int e = 0; e < E; e++) {
        float w0 = W[(0 * H + j) * E + e];
        float w1 = W[(1 * H + j) * E + e];
        float w2 = W[(2 * H + j) * E + e];
        float w3 = W[(3 * H + j) * E + e];
        #pragma unroll
        for (int v = 0; v < 16; v++) {
            float x = es[v * E + e];
            acc[0][v] += w0 * x; acc[1][v] += w1 * x;
            acc[2][v] += w2 * x; acc[3][v] += w3 * x;
        }
    }
    for (int v = 0; v < 16; v++)
        #pragma unroll
        for (int q = 0; q < 4; q++)
            pe[(vb * 16 + v) * G4 + q * H + j] = acc[q][v];
}

/* streamed-W layout: wstr[(d*WSTR + g)*1024 + r] = {W_d[r][92+4g .. +3]}
   -> per step, lane r loads consecutive float4 (coalesced 1 KB/wave-inst) */
__global__ __launch_bounds__(256) void k_prep(const float* __restrict__ whhf,
                                              const float* __restrict__ whhb,
                                              char* __restrict__ ws) {
    int tid = blockIdx.x * 256 + threadIdx.x;   /* 2*41*1024 = 83968 */
    if (tid >= 2 * WSTR * 1024) return;
    int d   = tid >= WSTR * 1024;
    int idx = d ? tid - WSTR * 1024 : tid;
    int g = idx >> 10, r = idx & 1023;
    const float* whh = d ? whhb : whhf;
    float4* wstr = (float4*)(ws + OFF_WSTREAM);
    const float4* src = (const float4*)(whh + (size_t)r * H + 4 * (WREG + WLDS));
    wstr[((size_t)(d * WSTR + g) << 10) + r] = src[g];
}

/* Single-CU LSTM: 256 blocks (dir d = blk>>7, batch b = blk&127) x 512 thr
   (8 waves, 2/SIMD; launch_bounds(512,2) -> 256-VGPR budget).
   Thread t owns gate rows t and t+512. Per row: cols [0,80) in VGPRs
   (PINNED via asm volatile -- R7's VGPR_Count=112 proved MachineLICM
   refuses to hoist 144 loop-invariant W loads; the pin forces residency),
   [80,92) in LDS, [92,256) streamed from L2 (656 KB/step, k-major).
   No cross-CU communication. 2 barriers/step. */
__global__ __launch_bounds__(512, 2) void k_lstm(const int* __restrict__ data,
                                                 const float* __restrict__ whhf,
                                                 const float* __restrict__ whhb,
                                                 const float* __restrict__ mlpW,
                                                 char* __restrict__ ws) {
    int blk = blockIdx.x;
    int d = blk >> 7, b = blk & 127;
    const float* whh = d ? whhb : whhf;
    const float* pe  = (const float*)(ws + (d ? OFF_PEMB_B : OFF_PEMB_F));
    float* emdst = (float*)(ws + (d ? OFF_EMB : OFF_EMF));
    const float4* wstr = (const float4*)(ws + OFF_WSTREAM) + ((size_t)(d * WSTR) << 10);

    __shared__ __align__(16) float hs[H];      /* h_prev, 1 KB */
    __shared__ float4 sW[WLDS << 10];          /* 48 KB */
    __shared__ float  gbuf[G4];                /* 4 KB */
    __shared__ float  red[T][4];
    __shared__ int    toks[S];                 /* 2 KB */

    int t = threadIdx.x;                       /* 0..511 */
    int r0 = t, r1 = t + 512;

    /* W register groups (cols 0..79) for both rows + LDS slab (cols 80..91) */
    const float4* wrow0 = (const float4*)(whh + (size_t)r0 * H);
    const float4* wrow1 = (const float4*)(whh + (size_t)r1 * H);
    float4 wA[WREG], wB[WREG];
    #pragma unroll
    for (int g = 0; g < WREG; g++) { wA[g] = wrow0[g]; wB[g] = wrow1[g]; }
    /* PIN: volatile asm consumes the loads pre-loop; results are loop-live
       VGPRs the compiler cannot sink, remat, or re-load. */
    #pragma unroll
    for (int g = 0; g < WREG; g++) {
        asm volatile("" : "+v"(wA[g].x), "+v"(wA[g].y), "+v"(wA[g].z), "+v"(wA[g].w));
        asm volatile("" : "+v"(wB[g].x), "+v"(wB[g].y), "+v"(wB[g].z), "+v"(wB[g].w));
    }
    #pragma unroll
    for (int g = 0; g < WLDS; g++) {
        sW[(g << 10) + r0] = wrow0[WREG + g];
        sW[(g << 10) + r1] = wrow1[WREG + g];
    }

    toks[t] = data[b * S + t];                 /* S == 512 == blockDim */

    float mw[T];
    if (t < 256) {
        #pragma unroll
        for (int tt = 0; tt < T; tt++) mw[tt] = mlpW[tt * (2 * H) + d * H + t];
    }
    if (t < H) hs[t] = 0.0f;
    float cst = 0.0f;
    __syncthreads();

    const float4* hs4 = (const float4*)hs;
    const float4* wsp0 = wstr + r0;
    const float4* wsp1 = wstr + r1;

    float pf0, pf1;
    {
        int sp0 = d ? (S - 1) : 0;
        size_t tok = (size_t)toks[sp0];
        pf0 = pe[(tok << 10) + r0];
        pf1 = pe[(tok << 10) + r1];
    }

    for (int ss = 0; ss < S; ss++) {
        int sp = d ? (S - 1 - ss) : ss;
        float acc0 = pf0, acc1 = pf1;
        if (ss + 1 < S) {
            int spn = d ? (S - 2 - ss) : (ss + 1);
            size_t tok = (size_t)toks[spn];
            pf0 = pe[(tok << 10) + r0];
            pf1 = pe[(tok << 10) + r1];
        }

        /* register-W phase: cols 0..79 (pinned VGPRs, zero memory traffic) */
        #pragma unroll
        for (int g = 0; g < WREG; g++) {
            float4 h4 = hs4[g];
            float4 a = wA[g], bb2 = wB[g];
            acc0 = fmaf(a.x, h4.x, acc0);  acc1 = fmaf(bb2.x, h4.x, acc1);
            acc0 = fmaf(a.y, h4.y, acc0);  acc1 = fmaf(bb2.y, h4.y, acc1);
            acc0 = fmaf(a.z, h4.z, acc0);  acc1 = fmaf(bb2.z, h4.z, acc1);
            acc0 = fmaf(a.w, h4.w, acc0);  acc1 = fmaf(bb2.w, h4.w, acc1);
        }
        /* LDS-W phase: cols 80..91 */
        #pragma unroll
        for (int g = 0; g < WLDS; g++) {
            float4 w0 = sW[(g << 10) + r0];
            float4 w1 = sW[(g << 10) + r1];
            float4 h4 = hs4[WREG + g];
            acc0 = fmaf(w0.x, h4.x, acc0);  acc1 = fmaf(w1.x, h4.x, acc1);
            acc0 = fmaf(w0.y, h4.y, acc0);  acc1 = fmaf(w1.y, h4.y, acc1);
            acc0 = fmaf(w0.z, h4.z, acc0);  acc1 = fmaf(w1.z, h4.z, acc1);
            acc0 = fmaf(w0.w, h4.w, acc0);  acc1 = fmaf(w1.w, h4.w, acc1);
        }
        /* streamed phase: cols 92..255 (bounded pipelining via unroll 4) */
        #pragma unroll 4
        for (int g = 0; g < WSTR; g++) {
            float4 w0 = wsp0[(size_t)g << 10];
            float4 w1 = wsp1[(size_t)g << 10];
            float4 h4 = hs4[WREG + WLDS + g];
            acc0 = fmaf(w0.x, h4.x, acc0);  acc1 = fmaf(w1.x, h4.x, acc1);
            acc0 = fmaf(w0.y, h4.y, acc0);  acc1 = fmaf(w1.y, h4.y, acc1);
            acc0 = fmaf(w0.z, h4.z, acc0);  acc1 = fmaf(w1.z, h4.z, acc1);
            acc0 = fmaf(w0.w, h4.w, acc0);  acc1 = fmaf(w1.w, h4.w, acc1);
        }
        gbuf[r0] = acc0;
        gbuf[r1] = acc1;
        __syncthreads();   /* B1: gates complete, hs reads done */

        if (t < 256) {
            float gi = gbuf[t], gf = gbuf[H + t], gg = gbuf[2 * H + t], go = gbuf[3 * H + t];
            float ig = sigf(gi), fg = sigf(gf), tg = tanhf(gg), og = sigf(go);
            cst = fg * cst + ig * tg;
            float hn = og * tanhf(cst);
            hs[t] = hn;
            int l = t & 63, wv = t >> 6;
            #pragma unroll
            for (int tt = 0; tt < T; tt++) {
                float v = hn * mw[tt];
                v += __shfl_xor(v, 32, 64); v += __shfl_xor(v, 16, 64);
                v += __shfl_xor(v, 8, 64);  v += __shfl_xor(v, 4, 64);
                v += __shfl_xor(v, 2, 64);  v += __shfl_xor(v, 1, 64);
                if (l == 0) red[tt][wv] = v;
            }
        }
        __syncthreads();   /* B2: hs updated + red ready */
        if (t < T)
            emdst[((size_t)b * S + sp) * T + t] = red[t][0] + red[t][1] + red[t][2] + red[t][3];
    }
}

/* Viterbi forward: one wave per batch, lane t = tag. Strict-> ascending scan
   matches jnp.argmax first-index tie-breaking. */
__global__ __launch_bounds__(64) void k_vit(const int* __restrict__ data,
                                            const float* __restrict__ strans,
                                            const float* __restrict__ trans,
                                            const float* __restrict__ etrans,
                                            const float* __restrict__ mlpb,
                                            float* __restrict__ out,
                                            char* __restrict__ ws) {
    int b = blockIdx.x, t = threadIdx.x;
    const float* emf = (const float*)(ws + OFF_EMF);
    const float* emb = (const float*)(ws + OFF_EMB);
    char* bp = ws + OFF_BP;
    int*  lt = (int*)(ws + OFF_LT);
    bool act = t < T;

    float trp[T];
    float mb = 0.0f;
    if (act) {
        #pragma unroll
        for (int p = 0; p < T; p++) trp[p] = trans[p * T + t];
        mb = mlpb[t];
    }
    float score = -1e30f;
    if (act) score = strans[t] + emf[(b * S) * T + t] + emb[(b * S) * T + t] + mb;

    for (int s = 1; s < S; s++) {
        float e = 0.0f;
        if (act) e = emf[(b * S + s) * T + t] + emb[(b * S + s) * T + t] + mb;
        float best = __shfl(score, 0, 64) + trp[0];
        int bpi = 0;
        #pragma unroll
        for (int p = 1; p < T; p++) {
            float cand = __shfl(score, p, 64) + trp[p];
            if (cand > best) { best = cand; bpi = p; }
        }
        int m = data[b * S + s] != 0;
        if (act) {
            score = m ? (best + e) : score;
            bp[((size_t)(s - 1) * B + b) * 16 + t] = (char)bpi;
        }
    }
    float fin = act ? score + etrans[t] : -1e30f;
    float bv = __shfl(fin, 0, 64);
    int bi = 0;
    #pragma unroll
    for (int p = 1; p < T; p++) {
        float v = __shfl(fin, p, 64);
        if (v > bv) { bv = v; bi = p; }
    }
    if (t == 0) { out[B * S + b] = bv; lt[b] = bi; }
}

/* Backtrack: thread = batch; bp row address is tag-independent -> pipelined loads */
__global__ __launch_bounds__(128) void k_back(const int* __restrict__ data, char* __restrict__ ws) {
    int b = threadIdx.x;
    const int4* bp4 = (const int4*)(ws + OFF_BP);
    const int*  lt  = (const int*)(ws + OFF_LT);
    int* pt = (int*)(ws + OFF_PT);
    int tag = lt[b];
    pt[(S - 1) * B + b] = tag;
    for (int p = S - 2; p >= 0; p--) {
        int4 r = bp4[(size_t)p * B + b];
        int m = data[b * S + p + 1] != 0;
        unsigned w = (unsigned)(tag < 8 ? (tag < 4 ? r.x : r.y) : r.z);
        int nt = (int)((w >> ((tag & 3) * 8)) & 0xff);
        tag = m ? nt : tag;
        pt[p * B + b] = tag;
    }
}

/* paths -> float output with mask zeroing */
__global__ __launch_bounds__(256) void k_fin(const int* __restrict__ data,
                                             float* __restrict__ out,
                                             const char* __restrict__ ws) {
    int tid = blockIdx.x * 256 + threadIdx.x;   /* 65536 */
    const int* pt = (const int*)(ws + OFF_PT);
    int b = tid >> 9, p = tid & 511;
    out[tid] = (data[tid] != 0) ? (float)pt[p * B + b] : 0.0f;
}

extern "C" void kernel_launch(void* const* d_in, const int* in_sizes, int n_in,
                              void* d_out, int out_size, void* d_ws, size_t ws_size,
                              hipStream_t stream) {
    const int*   data = (const int*)d_in[0];
    /* d_in[1] = mask (bool) — unused; mask == (data != 0) */
    const float* emb  = (const float*)d_in[2];
    const float* wihf = (const float*)d_in[3];
    const float* whhf = (const float*)d_in[4];
    const float* bf   = (const float*)d_in[5];
    const float* wihb = (const float*)d_in[6];
    const float* whhb = (const float*)d_in[7];
    const float* bb   = (const float*)d_in[8];
    const float* mlpW = (const float*)d_in[9];
    const float* mlpb = (const float*)d_in[10];
    const float* st   = (const float*)d_in[11];
    const float* tr   = (const float*)d_in[12];
    const float* et   = (const float*)d_in[13];
    float* out = (float*)d_out;
    char*  ws  = (char*)d_ws;

    hipLaunchKernelGGL(k_pemb, dim3(750),  dim3(256), 0, stream, emb, wihf, bf, wihb, bb, ws);
    hipLaunchKernelGGL(k_prep, dim3(328),  dim3(256), 0, stream, whhf, whhb, ws);
    hipLaunchKernelGGL(k_lstm, dim3(256),  dim3(512), 0, stream, data, whhf, whhb, mlpW, ws);
    hipLaunchKernelGGL(k_vit,  dim3(128),  dim3(64),  0, stream, data, st, tr, et, mlpb, out, ws);
    hipLaunchKernelGGL(k_back, dim3(1),    dim3(128), 0, stream, data, ws);
    hipLaunchKernelGGL(k_fin,  dim3(256),  dim3(256), 0, stream, data, out, ws);
}

// Round 9
// 4776.672 us; speedup vs baseline: 2.2400x; 1.0066x over previous
//
#include <hip/hip_runtime.h>
#include <math.h>
#include <stdint.h>

#define B 128
#define S 512
#define V 6000
#define E 100
#define H 256
#define G4 1024   /* 4*H */
#define T 9

/* W column split (float4 k-groups, 64 total = 256 cols per row) */
#define WREG 20            /* cols [0,80)  in VGPRs: 2 rows x 20 x 4 = 160 regs, PINNED */
#define WLDS 3             /* cols [80,92) in LDS slab (48 KB) */
#define WSTR 41            /* cols [92,256) streamed (656 KB/step/dir) */

/* workspace byte offsets (256-aligned) */
#define OFF_PEMB_F 0u
#define PEMB_BYTES (V*G4*4u)                    /* 24,576,000 */
#define OFF_PEMB_B (OFF_PEMB_F + PEMB_BYTES)
#define OFF_EMF    (OFF_PEMB_B + PEMB_BYTES)    /* 49,152,000 */
#define EM_BYTES   (B*S*T*4u)                   /* 2,359,296 */
#define OFF_EMB    (OFF_EMF + EM_BYTES)
#define OFF_BP     (OFF_EMB + EM_BYTES)         /* 53,870,592 */
#define BP_BYTES   ((S-1)*B*16u)                /* 1,046,528 */
#define OFF_LT     (OFF_BP + BP_BYTES)
#define OFF_PT     (OFF_LT + 512u)
/* Streamed-W (2 dirs x 41 groups x 1024 rows x 16 B = 1,343,488 B) OVERLAPS
   the BP/LT/PT region: k_prep writes it and k_lstm reads it strictly BEFORE
   k_vit/k_back write BP/LT/PT (stream-ordered). */
#define OFF_WSTREAM OFF_BP

__device__ __forceinline__ float sigf(float x) { return 1.0f / (1.0f + expf(-x)); }

/* pemb[v][g4] = bias[g4] + sum_e emb[v][e] * W_ih[g4][e],  g4 = q*H + j */
__global__ __launch_bounds__(256) void k_pemb(const float* __restrict__ emb,
                                              const float* __restrict__ wf, const float* __restrict__ bf,
                                              const float* __restrict__ wb, const float* __restrict__ bb,
                                              char* __restrict__ ws) {
    int blk = blockIdx.x;                   /* 0..749 */
    int d   = blk >= 375;
    int vb  = d ? blk - 375 : blk;
    const float* W    = d ? wb : wf;
    const float* bias = d ? bb : bf;
    float* pe = (float*)(ws + (d ? OFF_PEMB_B : OFF_PEMB_F));

    __shared__ float es[16 * E];
    for (int i = threadIdx.x; i < 16 * E; i += 256) es[i] = emb[vb * 16 * E + i];
    __syncthreads();

    int j = threadIdx.x;
    float acc[4][16];
    #pragma unroll
    for (int q = 0; q < 4; q++) {
        float bq = bias[q * H + j];
        #pragma unroll
        for (int v = 0; v < 16; v++) acc[q][v] = bq;
    }
    for (int e = 0; e < E; e++) {
        float w0 = W[(0 * H + j) * E + e];
        float w1 = W[(1 * H + j) * E + e];
        float w2 = W[(2 * H + j) * E + e];
        float w3 = W[(3 * H + j) * E + e];
        #pragma unroll
        for (int v = 0; v < 16; v++) {
            float x = es[v * E + e];
            acc[0][v] += w0 * x; acc[1][v] += w1 * x;
            acc[2][v] += w2 * x; acc[3][v] += w3 * x;
        }
    }
    for (int v = 0; v < 16; v++)
        #pragma unroll
        for (int q = 0; q < 4; q++)
            pe[(vb * 16 + v) * G4 + q * H + j] = acc[q][v];
}

/* streamed-W layout: wstr[(d*WSTR + g)*1024 + r] = {W_d[r][92+4g .. +3]}
   -> per step, lane r loads consecutive float4 (coalesced 1 KB/wave-inst) */
__global__ __launch_bounds__(256) void k_prep(const float* __restrict__ whhf,
                                              const float* __restrict__ whhb,
                                              char* __restrict__ ws) {
    int tid = blockIdx.x * 256 + threadIdx.x;   /* 2*41*1024 = 83968 */
    if (tid >= 2 * WSTR * 1024) return;
    int d   = tid >= WSTR * 1024;
    int idx = d ? tid - WSTR * 1024 : tid;
    int g = idx >> 10, r = idx & 1023;
    const float* whh = d ? whhb : whhf;
    float4* wstr = (float4*)(ws + OFF_WSTREAM);
    const float4* src = (const float4*)(whh + (size_t)r * H + 4 * (WREG + WLDS));
    wstr[((size_t)(d * WSTR + g) << 10) + r] = src[g];
}

/* Single-CU LSTM: 256 blocks (dir d = blk>>7, batch b = blk&127) x 512 thr.
   amdgpu_waves_per_eu(2,2) pins occupancy to EXACTLY 2 waves/EU (1 block/CU):
   R8 proved __launch_bounds__(512,2) is only a permission -- the allocator
   chased 4 waves/SIMD (128-reg cap) and spilled the 160 pinned W values to
   scratch, reloading per step (VGPR_Count=120, step time unchanged). With
   max=2 the 256-reg budget is the KNOWN occupancy, so keeping W live is free.
   Thread t owns gate rows t and t+512. Per row: cols [0,80) in VGPRs (pinned),
   [80,92) in LDS, [92,256) streamed from L2 (656 KB/step, k-major).
   No cross-CU communication. 2 barriers/step. */
__global__ __attribute__((amdgpu_flat_work_group_size(512, 512), amdgpu_waves_per_eu(2, 2)))
void k_lstm(const int* __restrict__ data,
            const float* __restrict__ whhf,
            const float* __restrict__ whhb,
            const float* __restrict__ mlpW,
            char* __restrict__ ws) {
    int blk = blockIdx.x;
    int d = blk >> 7, b = blk & 127;
    const float* whh = d ? whhb : whhf;
    const float* pe  = (const float*)(ws + (d ? OFF_PEMB_B : OFF_PEMB_F));
    float* emdst = (float*)(ws + (d ? OFF_EMB : OFF_EMF));
    const float4* wstr = (const float4*)(ws + OFF_WSTREAM) + ((size_t)(d * WSTR) << 10);

    __shared__ __align__(16) float hs[H];      /* h_prev, 1 KB */
    __shared__ float4 sW[WLDS << 10];          /* 48 KB */
    __shared__ float  gbuf[G4];                /* 4 KB */
    __shared__ float  red[T][4];
    __shared__ int    toks[S];                 /* 2 KB */

    int t = threadIdx.x;                       /* 0..511 */
    int r0 = t, r1 = t + 512;

    /* W register groups (cols 0..79) for both rows + LDS slab (cols 80..91) */
    const float4* wrow0 = (const float4*)(whh + (size_t)r0 * H);
    const float4* wrow1 = (const float4*)(whh + (size_t)r1 * H);
    float4 wA[WREG], wB[WREG];
    #pragma unroll
    for (int g = 0; g < WREG; g++) { wA[g] = wrow0[g]; wB[g] = wrow1[g]; }
    /* consume the loads pre-loop; with occupancy pinned the allocator keeps
       these live in VGPRs instead of spill/reload */
    #pragma unroll
    for (int g = 0; g < WREG; g++) {
        asm volatile("" : "+v"(wA[g].x), "+v"(wA[g].y), "+v"(wA[g].z), "+v"(wA[g].w));
        asm volatile("" : "+v"(wB[g].x), "+v"(wB[g].y), "+v"(wB[g].z), "+v"(wB[g].w));
    }
    #pragma unroll
    for (int g = 0; g < WLDS; g++) {
        sW[(g << 10) + r0] = wrow0[WREG + g];
        sW[(g << 10) + r1] = wrow1[WREG + g];
    }

    toks[t] = data[b * S + t];                 /* S == 512 == blockDim */

    float mw[T];
    if (t < 256) {
        #pragma unroll
        for (int tt = 0; tt < T; tt++) mw[tt] = mlpW[tt * (2 * H) + d * H + t];
    }
    if (t < H) hs[t] = 0.0f;
    float cst = 0.0f;
    __syncthreads();

    const float4* hs4 = (const float4*)hs;
    const float4* wsp0 = wstr + r0;
    const float4* wsp1 = wstr + r1;

    float pf0, pf1;
    {
        int sp0 = d ? (S - 1) : 0;
        size_t tok = (size_t)toks[sp0];
        pf0 = pe[(tok << 10) + r0];
        pf1 = pe[(tok << 10) + r1];
    }

    for (int ss = 0; ss < S; ss++) {
        int sp = d ? (S - 1 - ss) : ss;
        float acc0 = pf0, acc1 = pf1;
        if (ss + 1 < S) {
            int spn = d ? (S - 2 - ss) : (ss + 1);
            size_t tok = (size_t)toks[spn];
            pf0 = pe[(tok << 10) + r0];
            pf1 = pe[(tok << 10) + r1];
        }

        /* register-W phase: cols 0..79 (pinned VGPRs, zero memory traffic) */
        #pragma unroll
        for (int g = 0; g < WREG; g++) {
            float4 h4 = hs4[g];
            float4 a = wA[g], bb2 = wB[g];
            acc0 = fmaf(a.x, h4.x, acc0);  acc1 = fmaf(bb2.x, h4.x, acc1);
            acc0 = fmaf(a.y, h4.y, acc0);  acc1 = fmaf(bb2.y, h4.y, acc1);
            acc0 = fmaf(a.z, h4.z, acc0);  acc1 = fmaf(bb2.z, h4.z, acc1);
            acc0 = fmaf(a.w, h4.w, acc0);  acc1 = fmaf(bb2.w, h4.w, acc1);
        }
        /* LDS-W phase: cols 80..91 */
        #pragma unroll
        for (int g = 0; g < WLDS; g++) {
            float4 w0 = sW[(g << 10) + r0];
            float4 w1 = sW[(g << 10) + r1];
            float4 h4 = hs4[WREG + g];
            acc0 = fmaf(w0.x, h4.x, acc0);  acc1 = fmaf(w1.x, h4.x, acc1);
            acc0 = fmaf(w0.y, h4.y, acc0);  acc1 = fmaf(w1.y, h4.y, acc1);
            acc0 = fmaf(w0.z, h4.z, acc0);  acc1 = fmaf(w1.z, h4.z, acc1);
            acc0 = fmaf(w0.w, h4.w, acc0);  acc1 = fmaf(w1.w, h4.w, acc1);
        }
        /* streamed phase: cols 92..255 (bounded pipelining via unroll 4) */
        #pragma unroll 4
        for (int g = 0; g < WSTR; g++) {
            float4 w0 = wsp0[(size_t)g << 10];
            float4 w1 = wsp1[(size_t)g << 10];
            float4 h4 = hs4[WREG + WLDS + g];
            acc0 = fmaf(w0.x, h4.x, acc0);  acc1 = fmaf(w1.x, h4.x, acc1);
            acc0 = fmaf(w0.y, h4.y, acc0);  acc1 = fmaf(w1.y, h4.y, acc1);
            acc0 = fmaf(w0.z, h4.z, acc0);  acc1 = fmaf(w1.z, h4.z, acc1);
            acc0 = fmaf(w0.w, h4.w, acc0);  acc1 = fmaf(w1.w, h4.w, acc1);
        }
        gbuf[r0] = acc0;
        gbuf[r1] = acc1;
        __syncthreads();   /* B1: gates complete, hs reads done */

        if (t < 256) {
            float gi = gbuf[t], gf = gbuf[H + t], gg = gbuf[2 * H + t], go = gbuf[3 * H + t];
            float ig = sigf(gi), fg = sigf(gf), tg = tanhf(gg), og = sigf(go);
            cst = fg * cst + ig * tg;
            float hn = og * tanhf(cst);
            hs[t] = hn;
            int l = t & 63, wv = t >> 6;
            #pragma unroll
            for (int tt = 0; tt < T; tt++) {
                float v = hn * mw[tt];
                v += __shfl_xor(v, 32, 64); v += __shfl_xor(v, 16, 64);
                v += __shfl_xor(v, 8, 64);  v += __shfl_xor(v, 4, 64);
                v += __shfl_xor(v, 2, 64);  v += __shfl_xor(v, 1, 64);
                if (l == 0) red[tt][wv] = v;
            }
        }
        __syncthreads();   /* B2: hs updated + red ready */
        if (t < T)
            emdst[((size_t)b * S + sp) * T + t] = red[t][0] + red[t][1] + red[t][2] + red[t][3];
    }
}

/* Viterbi forward: one wave per batch, lane t = tag. Strict-> ascending scan
   matches jnp.argmax first-index tie-breaking. */
__global__ __launch_bounds__(64) void k_vit(const int* __restrict__ data,
                                            const float* __restrict__ strans,
                                            const float* __restrict__ trans,
                                            const float* __restrict__ etrans,
                                            const float* __restrict__ mlpb,
                                            float* __restrict__ out,
                                            char* __restrict__ ws) {
    int b = blockIdx.x, t = threadIdx.x;
    const float* emf = (const float*)(ws + OFF_EMF);
    const float* emb = (const float*)(ws + OFF_EMB);
    char* bp = ws + OFF_BP;
    int*  lt = (int*)(ws + OFF_LT);
    bool act = t < T;

    float trp[T];
    float mb = 0.0f;
    if (act) {
        #pragma unroll
        for (int p = 0; p < T; p++) trp[p] = trans[p * T + t];
        mb = mlpb[t];
    }
    float score = -1e30f;
    if (act) score = strans[t] + emf[(b * S) * T + t] + emb[(b * S) * T + t] + mb;

    for (int s = 1; s < S; s++) {
        float e = 0.0f;
        if (act) e = emf[(b * S + s) * T + t] + emb[(b * S + s) * T + t] + mb;
        float best = __shfl(score, 0, 64) + trp[0];
        int bpi = 0;
        #pragma unroll
        for (int p = 1; p < T; p++) {
            float cand = __shfl(score, p, 64) + trp[p];
            if (cand > best) { best = cand; bpi = p; }
        }
        int m = data[b * S + s] != 0;
        if (act) {
            score = m ? (best + e) : score;
            bp[((size_t)(s - 1) * B + b) * 16 + t] = (char)bpi;
        }
    }
    float fin = act ? score + etrans[t] : -1e30f;
    float bv = __shfl(fin, 0, 64);
    int bi = 0;
    #pragma unroll
    for (int p = 1; p < T; p++) {
        float v = __shfl(fin, p, 64);
        if (v > bv) { bv = v; bi = p; }
    }
    if (t == 0) { out[B * S + b] = bv; lt[b] = bi; }
}

/* Backtrack: thread = batch; bp row address is tag-independent -> pipelined loads */
__global__ __launch_bounds__(128) void k_back(const int* __restrict__ data, char* __restrict__ ws) {
    int b = threadIdx.x;
    const int4* bp4 = (const int4*)(ws + OFF_BP);
    const int*  lt  = (const int*)(ws + OFF_LT);
    int* pt = (int*)(ws + OFF_PT);
    int tag = lt[b];
    pt[(S - 1) * B + b] = tag;
    for (int p = S - 2; p >= 0; p--) {
        int4 r = bp4[(size_t)p * B + b];
        int m = data[b * S + p + 1] != 0;
        unsigned w = (unsigned)(tag < 8 ? (tag < 4 ? r.x : r.y) : r.z);
        int nt = (int)((w >> ((tag & 3) * 8)) & 0xff);
        tag = m ? nt : tag;
        pt[p * B + b] = tag;
    }
}

/* paths -> float output with mask zeroing */
__global__ __launch_bounds__(256) void k_fin(const int* __restrict__ data,
                                             float* __restrict__ out,
                                             const char* __restrict__ ws) {
    int tid = blockIdx.x * 256 + threadIdx.x;   /* 65536 */
    const int* pt = (const int*)(ws + OFF_PT);
    int b = tid >> 9, p = tid & 511;
    out[tid] = (data[tid] != 0) ? (float)pt[p * B + b] : 0.0f;
}

extern "C" void kernel_launch(void* const* d_in, const int* in_sizes, int n_in,
                              void* d_out, int out_size, void* d_ws, size_t ws_size,
                              hipStream_t stream) {
    const int*   data = (const int*)d_in[0];
    /* d_in[1] = mask (bool) — unused; mask == (data != 0) */
    const float* emb  = (const float*)d_in[2];
    const float* wihf = (const float*)d_in[3];
    const float* whhf = (const float*)d_in[4];
    const float* bf   = (const float*)d_in[5];
    const float* wihb = (const float*)d_in[6];
    const float* whhb = (const float*)d_in[7];
    const float* bb   = (const float*)d_in[8];
    const float* mlpW = (const float*)d_in[9];
    const float* mlpb = (const float*)d_in[10];
    const float* st   = (const float*)d_in[11];
    const float* tr   = (const float*)d_in[12];
    const float* et   = (const float*)d_in[13];
    float* out = (float*)d_out;
    char*  ws  = (char*)d_ws;

    hipLaunchKernelGGL(k_pemb, dim3(750),  dim3(256), 0, stream, emb, wihf, bf, wihb, bb, ws);
    hipLaunchKernelGGL(k_prep, dim3(328),  dim3(256), 0, stream, whhf, whhb, ws);
    hipLaunchKernelGGL(k_lstm, dim3(256),  dim3(512), 0, stream, data, whhf, whhb, mlpW, ws);
    hipLaunchKernelGGL(k_vit,  dim3(128),  dim3(64),  0, stream, data, st, tr, et, mlpb, out, ws);
    hipLaunchKernelGGL(k_back, dim3(1),    dim3(128), 0, stream, data, ws);
    hipLaunchKernelGGL(k_fin,  dim3(256),  dim3(256), 0, stream, data, out, ws);
}